// Round 4
// baseline (603.128 us; speedup 1.0000x reference)
//
#include <hip/hip_runtime.h>
#include <hip/hip_bf16.h>
#include <math.h>

#define LEAKY 0.01f
#define SCAN_BLOCK 256
#define SCAN_ITEMS 4
#define SCAN_TILE (SCAN_BLOCK * SCAN_ITEMS)  // 1024 items per block

__global__ void zero_i32(int* __restrict__ p, int n) {
    int i = blockIdx.x * blockDim.x + threadIdx.x;
    if (i < n) p[i] = 0;
}

// counts degree AND records each edge's rank within its row (kills fill atomic)
__global__ void count_edges(const int* __restrict__ row, int E,
                            int* __restrict__ deg, int* __restrict__ rank) {
    int i = blockIdx.x * blockDim.x + threadIdx.x;
    if (i < E) rank[i] = atomicAdd(&deg[row[i]], 1);
}

// ---- 3-phase device-wide exclusive scan of deg[N] -> row_ptr[N+1] ----
__global__ __launch_bounds__(SCAN_BLOCK) void scan_phase1(
    const int* __restrict__ deg, int* __restrict__ blocksum, int N) {
    __shared__ int red[SCAN_BLOCK];
    int b = blockIdx.x, t = threadIdx.x;
    int base = b * SCAN_TILE + t * SCAN_ITEMS;
    int s = 0;
#pragma unroll
    for (int j = 0; j < SCAN_ITEMS; j++) {
        int i = base + j;
        if (i < N) s += deg[i];
    }
    red[t] = s;
    __syncthreads();
    for (int off = SCAN_BLOCK / 2; off > 0; off >>= 1) {
        if (t < off) red[t] += red[t + off];
        __syncthreads();
    }
    if (t == 0) blocksum[b] = red[0];
}

__global__ __launch_bounds__(1024) void scan_phase2(
    const int* __restrict__ blocksum, int* __restrict__ blockoff,
    int* __restrict__ row_ptr, int G, int N) {
    __shared__ int sums[1024];
    int t = threadIdx.x;
    sums[t] = (t < G) ? blocksum[t] : 0;
    __syncthreads();
    for (int off = 1; off < 1024; off <<= 1) {
        int v = (t >= off) ? sums[t - off] : 0;
        __syncthreads();
        sums[t] += v;
        __syncthreads();
    }
    if (t < G) blockoff[t] = (t == 0) ? 0 : sums[t - 1];
    if (t == G - 1) row_ptr[N] = sums[t];
}

__global__ __launch_bounds__(SCAN_BLOCK) void scan_phase3(
    const int* __restrict__ deg, const int* __restrict__ blockoff,
    int* __restrict__ row_ptr, int N) {
    __shared__ int red[SCAN_BLOCK];
    int b = blockIdx.x, t = threadIdx.x;
    int base = b * SCAN_TILE + t * SCAN_ITEMS;
    int v[SCAN_ITEMS];
    int s = 0;
#pragma unroll
    for (int j = 0; j < SCAN_ITEMS; j++) {
        int i = base + j;
        v[j] = (i < N) ? deg[i] : 0;
        s += v[j];
    }
    red[t] = s;
    __syncthreads();
    for (int off = 1; off < SCAN_BLOCK; off <<= 1) {
        int x = (t >= off) ? red[t - off] : 0;
        __syncthreads();
        red[t] += x;
        __syncthreads();
    }
    int run = blockoff[b] + ((t == 0) ? 0 : red[t - 1]);
#pragma unroll
    for (int j = 0; j < SCAN_ITEMS; j++) {
        int i = base + j;
        if (i < N) { row_ptr[i] = run; run += v[j]; }
    }
}
// ----------------------------------------------------------------------

// a0 = concat(user_embed, entity_embed), contiguous N x 64
__global__ void build_a0(const float4* __restrict__ ue, const float4* __restrict__ ee,
                         float4* __restrict__ a0, int nu4, int ntot4) {
    int i = blockIdx.x * blockDim.x + threadIdx.x;
    if (i < ntot4) a0[i] = (i < nu4) ? ue[i] : ee[i - nu4];
}

// atomic-free CSR fill using precomputed ranks
__global__ void fill_csr(const int* __restrict__ row, const int* __restrict__ col,
                         const float* __restrict__ val, const int* __restrict__ rank,
                         const int* __restrict__ row_ptr, int E,
                         int2* __restrict__ csr) {
    int i = blockIdx.x * blockDim.x + threadIdx.x;
    if (i < E) {
        int p = row_ptr[row[i]] + rank[i];
        csr[p] = make_int2(col[i], __float_as_int(val[i]));
    }
}

// Fused GNN layer, register-resident weights.
// Block = 512 thr (8 waves). Weights staged to LDS once per block, then each
// lane pulls its output column(s) into VGPRs (DOUT=64: 128 regs; DOUT=32:
// lanes 0-31 hold W1 col, lanes 32-63 hold W2 col, combined via shfl_xor(32)).
// Each wave loops over 8 nodes: gather-aggregate -> s1/s2 to per-wave LDS ->
// MLP from registers with broadcast s-reads (~0.6 KB LDS/node vs 32 KB before).
template<int DOUT>
__global__ __launch_bounds__(512, 3) void gnn_layer(
    const float* __restrict__ feats, const int2* __restrict__ csr,
    const int* __restrict__ row_ptr,
    const float* __restrict__ W1, const float* __restrict__ b1,
    const float* __restrict__ W2, const float* __restrict__ b2,
    float* __restrict__ out, int N) {
    constexpr int NPW = 8;            // nodes per wave
    constexpr int NPB = NPW * 8;      // 64 nodes per block
    __shared__ __align__(16) float wlds[(DOUT == 64) ? 8192 : 4096];
    __shared__ __align__(16) float sbuf[8][128];

    if constexpr (DOUT == 64) {
        for (int i = threadIdx.x; i < 4096; i += 512) {
            wlds[i]        = W1[i];
            wlds[4096 + i] = W2[i];
        }
    } else {
        // pack half-wise: wlds[k*64 + 0..31] = W1[k][*], [32..63] = W2[k][*]
        for (int i = threadIdx.x; i < 2048; i += 512) {
            int k = i >> 5, d = i & 31;
            wlds[k * 64 + d]      = W1[i];
            wlds[k * 64 + 32 + d] = W2[i];
        }
    }
    __syncthreads();

    int wv = threadIdx.x >> 6, lane = threadIdx.x & 63;

    // pull weight column(s) into registers (conflict-free: bank = lane%32, 2-way)
    float wc1[64];
    float wc2[(DOUT == 64) ? 64 : 1];
#pragma unroll
    for (int k = 0; k < 64; k++) {
        wc1[k] = wlds[k * 64 + lane];
        if constexpr (DOUT == 64) wc2[k] = wlds[4096 + k * 64 + lane];
    }
    float bias;
    if constexpr (DOUT == 64) bias = b1[lane] + b2[lane];
    else { int d = lane & 31; bias = b1[d] + b2[d]; }

    float* sp = sbuf[wv];
    int node0 = blockIdx.x * NPB + wv * NPW;
    for (int ni = 0; ni < NPW; ni++) {
        int node = node0 + ni;
        if (node >= N) return;
        float x = feats[node * 64 + lane];
        int e0 = row_ptr[node], e1 = row_ptr[node + 1];
        float acc = 0.f;
        int e = e0;
        for (; e + 4 <= e1; e += 4) {
            int2 p0 = csr[e], p1 = csr[e + 1], p2 = csr[e + 2], p3 = csr[e + 3];
            float f0 = feats[p0.x * 64 + lane];
            float f1 = feats[p1.x * 64 + lane];
            float f2 = feats[p2.x * 64 + lane];
            float f3 = feats[p3.x * 64 + lane];
            acc = fmaf(__int_as_float(p0.y), f0, acc);
            acc = fmaf(__int_as_float(p1.y), f1, acc);
            acc = fmaf(__int_as_float(p2.y), f2, acc);
            acc = fmaf(__int_as_float(p3.y), f3, acc);
        }
        for (; e < e1; e++) {
            int2 p = csr[e];
            acc = fmaf(__int_as_float(p.y), feats[p.x * 64 + lane], acc);
        }
        sp[lane]      = x + acc;   // s1
        sp[64 + lane] = x * acc;   // s2
        __threadfence_block();     // order intra-wave LDS write -> cross-lane read

        float h;
        if constexpr (DOUT == 64) {
            float o = bias;
#pragma unroll
            for (int k = 0; k < 64; k += 4) {
                float4 s1v = *(const float4*)&sp[k];        // broadcast (free)
                float4 s2v = *(const float4*)&sp[64 + k];
                o = fmaf(s1v.x, wc1[k],     o); o = fmaf(s2v.x, wc2[k],     o);
                o = fmaf(s1v.y, wc1[k + 1], o); o = fmaf(s2v.y, wc2[k + 1], o);
                o = fmaf(s1v.z, wc1[k + 2], o); o = fmaf(s2v.z, wc2[k + 2], o);
                o = fmaf(s1v.w, wc1[k + 3], o); o = fmaf(s2v.w, wc2[k + 3], o);
            }
            h = (o > 0.f) ? o : LEAKY * o;
        } else {
            const float* sh = sp + ((lane >= 32) ? 64 : 0);  // s1 | s2 half
            float part = 0.f;
#pragma unroll
            for (int k = 0; k < 64; k += 4) {
                float4 sv = *(const float4*)&sh[k];
                part = fmaf(sv.x, wc1[k],     part);
                part = fmaf(sv.y, wc1[k + 1], part);
                part = fmaf(sv.z, wc1[k + 2], part);
                part = fmaf(sv.w, wc1[k + 3], part);
            }
            float o = bias + part + __shfl_xor(part, 32, 64);
            h = (o > 0.f) ? o : LEAKY * o;
        }
        float ss = h * h;
        if constexpr (DOUT == 64) {
#pragma unroll
            for (int m = 32; m >= 1; m >>= 1) ss += __shfl_xor(ss, m, 64);
        } else {
#pragma unroll
            for (int m = 16; m >= 1; m >>= 1) ss += __shfl_xor(ss, m, 64);
        }
        float scale = 1.0f / fmaxf(sqrtf(ss), 1e-12f);
        if constexpr (DOUT == 64) {
            out[node * 64 + lane] = h * scale;
        } else {
            if (lane < 32) out[node * 32 + lane] = h * scale;
        }
    }
}

// final = concat(a0, a1, a2); score[b] = dot(final[u], final[NU+i]) over 160 dims
__global__ __launch_bounds__(256) void score_pairs(
    const float* __restrict__ a0, const float* __restrict__ a1,
    const float* __restrict__ a2,
    const int* __restrict__ uid, const int* __restrict__ iid,
    float* __restrict__ out, int B, int NU) {
    int wave = threadIdx.x >> 6, lane = threadIdx.x & 63;
    int p = blockIdx.x * 4 + wave;
    if (p >= B) return;
    int u = uid[p], it = iid[p];
    size_t un = (size_t)u, in = (size_t)(NU + it);
    float s = a0[un * 64 + lane] * a0[in * 64 + lane];
    s = fmaf(a1[un * 64 + lane], a1[in * 64 + lane], s);
    if (lane < 32) s = fmaf(a2[un * 32 + lane], a2[in * 32 + lane], s);
#pragma unroll
    for (int m = 32; m >= 1; m >>= 1) s += __shfl_xor(s, m, 64);
    if (lane == 0) out[p] = s;
}

extern "C" void kernel_launch(void* const* d_in, const int* in_sizes, int n_in,
                              void* d_out, int out_size, void* d_ws, size_t ws_size,
                              hipStream_t stream) {
    const int*   edge_row  = (const int*)d_in[0];
    const int*   edge_col  = (const int*)d_in[1];
    const float* edge_vals = (const float*)d_in[2];
    const float* ue        = (const float*)d_in[3];
    const float* ee        = (const float*)d_in[4];
    const float* W1_0 = (const float*)d_in[5];
    const float* b1_0 = (const float*)d_in[6];
    const float* W2_0 = (const float*)d_in[7];
    const float* b2_0 = (const float*)d_in[8];
    const float* W1_1 = (const float*)d_in[9];
    const float* b1_1 = (const float*)d_in[10];
    const float* W2_1 = (const float*)d_in[11];
    const float* b2_1 = (const float*)d_in[12];
    const int*   uid  = (const int*)d_in[13];
    const int*   iid  = (const int*)d_in[14];
    float* out = (float*)d_out;

    const int E  = in_sizes[0];
    const int NU = in_sizes[3] / 64;
    const int NE = in_sizes[4] / 64;
    const int N  = NU + NE;
    const int B  = in_sizes[13];
    const int G  = (N + SCAN_TILE - 1) / SCAN_TILE;

    char* ws = (char*)d_ws;
    size_t off = 0;
    auto alloc = [&](size_t bytes) -> char* {
        char* p = ws + off;
        off = (off + bytes + 255) & ~(size_t)255;
        return p;
    };
    int*   deg      = (int*)alloc((size_t)N * 4);
    int*   rank     = (int*)alloc((size_t)E * 4);
    int*   row_ptr  = (int*)alloc((size_t)(N + 1) * 4);
    int*   blocksum = (int*)alloc((size_t)1024 * 4);
    int*   blockoff = (int*)alloc((size_t)1024 * 4);
    int2*  csr      = (int2*)alloc((size_t)E * 8);
    float* a0       = (float*)alloc((size_t)N * 64 * 4);
    float* a1       = (float*)alloc((size_t)N * 64 * 4);
    float* a2       = (float*)alloc((size_t)N * 32 * 4);
    (void)ws_size; (void)n_in; (void)out_size; (void)NE;

    zero_i32<<<(N + 255) / 256, 256, 0, stream>>>(deg, N);
    count_edges<<<(E + 255) / 256, 256, 0, stream>>>(edge_row, E, deg, rank);
    scan_phase1<<<G, SCAN_BLOCK, 0, stream>>>(deg, blocksum, N);
    scan_phase2<<<1, 1024, 0, stream>>>(blocksum, blockoff, row_ptr, G, N);
    scan_phase3<<<G, SCAN_BLOCK, 0, stream>>>(deg, blockoff, row_ptr, N);
    fill_csr<<<(E + 255) / 256, 256, 0, stream>>>(edge_row, edge_col, edge_vals,
                                                  rank, row_ptr, E, csr);
    int ntot4 = N * 16, nu4 = NU * 16;
    build_a0<<<(ntot4 + 255) / 256, 256, 0, stream>>>((const float4*)ue, (const float4*)ee,
                                                      (float4*)a0, nu4, ntot4);
    gnn_layer<64><<<(N + 63) / 64, 512, 0, stream>>>(a0, csr, row_ptr,
                                                     W1_0, b1_0, W2_0, b2_0, a1, N);
    gnn_layer<32><<<(N + 63) / 64, 512, 0, stream>>>(a1, csr, row_ptr,
                                                     W1_1, b1_1, W2_1, b2_1, a2, N);
    score_pairs<<<(B + 3) / 4, 256, 0, stream>>>(a0, a1, a2, uid, iid, out, B, NU);
}

// Round 6
// 455.681 us; speedup vs baseline: 1.3236x; 1.3236x over previous
//
#include <hip/hip_runtime.h>
#include <hip/hip_bf16.h>
#include <math.h>

#define LEAKY 0.01f
#define SCAN_BLOCK 256
#define SCAN_ITEMS 4
#define SCAN_TILE (SCAN_BLOCK * SCAN_ITEMS)  // 1024 items per block

__global__ void zero_i32(int* __restrict__ p, int n) {
    int i = blockIdx.x * blockDim.x + threadIdx.x;
    if (i < n) p[i] = 0;
}

// counts degree AND records each edge's rank within its row (kills fill atomic)
__global__ void count_edges(const int* __restrict__ row, int E,
                            int* __restrict__ deg, int* __restrict__ rank) {
    int i = blockIdx.x * blockDim.x + threadIdx.x;
    if (i < E) rank[i] = atomicAdd(&deg[row[i]], 1);
}

// ---- 3-phase device-wide exclusive scan of deg[N] -> row_ptr[N+1] ----
__global__ __launch_bounds__(SCAN_BLOCK) void scan_phase1(
    const int* __restrict__ deg, int* __restrict__ blocksum, int N) {
    __shared__ int red[SCAN_BLOCK];
    int b = blockIdx.x, t = threadIdx.x;
    int base = b * SCAN_TILE + t * SCAN_ITEMS;
    int s = 0;
#pragma unroll
    for (int j = 0; j < SCAN_ITEMS; j++) {
        int i = base + j;
        if (i < N) s += deg[i];
    }
    red[t] = s;
    __syncthreads();
    for (int off = SCAN_BLOCK / 2; off > 0; off >>= 1) {
        if (t < off) red[t] += red[t + off];
        __syncthreads();
    }
    if (t == 0) blocksum[b] = red[0];
}

__global__ __launch_bounds__(1024) void scan_phase2(
    const int* __restrict__ blocksum, int* __restrict__ blockoff,
    int* __restrict__ row_ptr, int G, int N) {
    __shared__ int sums[1024];
    int t = threadIdx.x;
    sums[t] = (t < G) ? blocksum[t] : 0;
    __syncthreads();
    for (int off = 1; off < 1024; off <<= 1) {
        int v = (t >= off) ? sums[t - off] : 0;
        __syncthreads();
        sums[t] += v;
        __syncthreads();
    }
    if (t < G) blockoff[t] = (t == 0) ? 0 : sums[t - 1];
    if (t == G - 1) row_ptr[N] = sums[t];
}

__global__ __launch_bounds__(SCAN_BLOCK) void scan_phase3(
    const int* __restrict__ deg, const int* __restrict__ blockoff,
    int* __restrict__ row_ptr, int N) {
    __shared__ int red[SCAN_BLOCK];
    int b = blockIdx.x, t = threadIdx.x;
    int base = b * SCAN_TILE + t * SCAN_ITEMS;
    int v[SCAN_ITEMS];
    int s = 0;
#pragma unroll
    for (int j = 0; j < SCAN_ITEMS; j++) {
        int i = base + j;
        v[j] = (i < N) ? deg[i] : 0;
        s += v[j];
    }
    red[t] = s;
    __syncthreads();
    for (int off = 1; off < SCAN_BLOCK; off <<= 1) {
        int x = (t >= off) ? red[t - off] : 0;
        __syncthreads();
        red[t] += x;
        __syncthreads();
    }
    int run = blockoff[b] + ((t == 0) ? 0 : red[t - 1]);
#pragma unroll
    for (int j = 0; j < SCAN_ITEMS; j++) {
        int i = base + j;
        if (i < N) { row_ptr[i] = run; run += v[j]; }
    }
}
// ----------------------------------------------------------------------

// a0 = concat(user_embed, entity_embed), contiguous N x 64
__global__ void build_a0(const float4* __restrict__ ue, const float4* __restrict__ ee,
                         float4* __restrict__ a0, int nu4, int ntot4) {
    int i = blockIdx.x * blockDim.x + threadIdx.x;
    if (i < ntot4) a0[i] = (i < nu4) ? ue[i] : ee[i - nu4];
}

// atomic-free CSR fill using precomputed ranks
__global__ void fill_csr(const int* __restrict__ row, const int* __restrict__ col,
                         const float* __restrict__ val, const int* __restrict__ rank,
                         const int* __restrict__ row_ptr, int E,
                         int2* __restrict__ csr) {
    int i = blockIdx.x * blockDim.x + threadIdx.x;
    if (i < E) {
        int p = row_ptr[row[i]] + rank[i];
        csr[p] = make_int2(col[i], __float_as_int(val[i]));
    }
}

__device__ __forceinline__ void fma4(float o[4], float sv, const float4& wv) {
    o[0] = fmaf(sv, wv.x, o[0]);
    o[1] = fmaf(sv, wv.y, o[1]);
    o[2] = fmaf(sv, wv.z, o[2]);
    o[3] = fmaf(sv, wv.w, o[3]);
}

// Fused GNN layer. Block = 256 thr (4 waves), 8 nodes per wave.
// Phase 1 (per wave, lane=dim): CSR gather-aggregate 8 nodes sequentially,
//   write s1|s2 rows (128 floats, stride 132 -> conflict-free) into LDS.
// Phase 2 (register-blocked MLP): weights read straight from GLOBAL (32 KB,
//   L1-resident, VMEM pipe) -- LDS holds only S. DOUT=64: each lane owns
//   2 nodes x 4 dims (8 accumulators); per 4-k chunk: 2 LDS b128 + 4 global
//   b128 for 32 FMAs -> 8 LDS instr/node vs 64 in the old layout.
// Then leaky_relu + L2-normalize (shfl reduce) + coalesced float4 store.
template<int DOUT>
__global__ __launch_bounds__(256, 4) void gnn_layer(
    const float* __restrict__ feats, const int2* __restrict__ csr,
    const int* __restrict__ row_ptr,
    const float* __restrict__ W1, const float* __restrict__ b1,
    const float* __restrict__ W2, const float* __restrict__ b2,
    float* __restrict__ out, int N) {
    __shared__ __align__(16) float S[32 * 132];
    int wv = threadIdx.x >> 6, lane = threadIdx.x & 63;
    int nb = blockIdx.x * 32 + wv * 8;  // first node of this wave

    // ---- phase 1: aggregate 8 nodes ----
    for (int ni = 0; ni < 8; ni++) {
        int node = nb + ni;
        if (node >= N) break;
        float x = feats[node * 64 + lane];
        int e0 = row_ptr[node], e1 = row_ptr[node + 1];
        float acc = 0.f;
        int e = e0;
        for (; e + 4 <= e1; e += 4) {
            int2 p0 = csr[e], p1 = csr[e + 1], p2 = csr[e + 2], p3 = csr[e + 3];
            float f0 = feats[p0.x * 64 + lane];
            float f1 = feats[p1.x * 64 + lane];
            float f2 = feats[p2.x * 64 + lane];
            float f3 = feats[p3.x * 64 + lane];
            acc = fmaf(__int_as_float(p0.y), f0, acc);
            acc = fmaf(__int_as_float(p1.y), f1, acc);
            acc = fmaf(__int_as_float(p2.y), f2, acc);
            acc = fmaf(__int_as_float(p3.y), f3, acc);
        }
        for (; e < e1; e++) {
            int2 p = csr[e];
            acc = fmaf(__int_as_float(p.y), feats[p.x * 64 + lane], acc);
        }
        float* sp = &S[(wv * 8 + ni) * 132];
        sp[lane]      = x + acc;  // s1
        sp[64 + lane] = x * acc;  // s2
    }
    __threadfence_block();  // wave-local LDS write -> cross-lane read ordering

    // ---- phase 2: MLP + epilogue ----
    if constexpr (DOUT == 64) {
        int strip = lane & 15, g = lane >> 4;    // 16 strips x 4 dims; 4 node-pairs
        int d0 = strip * 4;
        float4 b1v = *(const float4*)&b1[d0];
        float4 b2v = *(const float4*)&b2[d0];
        float oa[4] = {b1v.x + b2v.x, b1v.y + b2v.y, b1v.z + b2v.z, b1v.w + b2v.w};
        float ob[4] = {oa[0], oa[1], oa[2], oa[3]};
        const float* spa = &S[(wv * 8 + 2 * g) * 132];
        const float* spb = spa + 132;
#pragma unroll
        for (int half = 0; half < 2; half++) {
            const float* W  = half ? W2 : W1;
            const float* sa = spa + half * 64;
            const float* sb = spb + half * 64;
#pragma unroll 2
            for (int k = 0; k < 64; k += 4) {
                float4 va = *(const float4*)&sa[k];
                float4 vb = *(const float4*)&sb[k];
                float4 wr0 = *(const float4*)&W[(k + 0) * 64 + d0];
                float4 wr1 = *(const float4*)&W[(k + 1) * 64 + d0];
                float4 wr2 = *(const float4*)&W[(k + 2) * 64 + d0];
                float4 wr3 = *(const float4*)&W[(k + 3) * 64 + d0];
                fma4(oa, va.x, wr0); fma4(oa, va.y, wr1);
                fma4(oa, va.z, wr2); fma4(oa, va.w, wr3);
                fma4(ob, vb.x, wr0); fma4(ob, vb.y, wr1);
                fma4(ob, vb.z, wr2); fma4(ob, vb.w, wr3);
            }
        }
#pragma unroll
        for (int t = 0; t < 2; t++) {
            float* o = t ? ob : oa;
            float h0 = (o[0] > 0.f) ? o[0] : LEAKY * o[0];
            float h1 = (o[1] > 0.f) ? o[1] : LEAKY * o[1];
            float h2 = (o[2] > 0.f) ? o[2] : LEAKY * o[2];
            float h3 = (o[3] > 0.f) ? o[3] : LEAKY * o[3];
            float ss = h0 * h0 + h1 * h1 + h2 * h2 + h3 * h3;
            ss += __shfl_xor(ss, 1, 64);
            ss += __shfl_xor(ss, 2, 64);
            ss += __shfl_xor(ss, 4, 64);
            ss += __shfl_xor(ss, 8, 64);   // 16 lanes = one node
            float sc = 1.0f / fmaxf(sqrtf(ss), 1e-12f);
            int node = nb + 2 * g + t;
            if (node < N) {
                float4 r = {h0 * sc, h1 * sc, h2 * sc, h3 * sc};
                *(float4*)&out[node * 64 + d0] = r;
            }
        }
    } else {
        int strip = lane & 7, nI = lane >> 3;    // 8 strips x 4 dims; 8 nodes
        int d0 = strip * 4;
        float4 b1v = *(const float4*)&b1[d0];
        float4 b2v = *(const float4*)&b2[d0];
        float o[4] = {b1v.x + b2v.x, b1v.y + b2v.y, b1v.z + b2v.z, b1v.w + b2v.w};
        const float* sp = &S[(wv * 8 + nI) * 132];
#pragma unroll
        for (int half = 0; half < 2; half++) {
            const float* W  = half ? W2 : W1;
            const float* sv = sp + half * 64;
#pragma unroll 2
            for (int k = 0; k < 64; k += 4) {
                float4 v   = *(const float4*)&sv[k];
                float4 wr0 = *(const float4*)&W[(k + 0) * 32 + d0];
                float4 wr1 = *(const float4*)&W[(k + 1) * 32 + d0];
                float4 wr2 = *(const float4*)&W[(k + 2) * 32 + d0];
                float4 wr3 = *(const float4*)&W[(k + 3) * 32 + d0];
                fma4(o, v.x, wr0); fma4(o, v.y, wr1);
                fma4(o, v.z, wr2); fma4(o, v.w, wr3);
            }
        }
        float h0 = (o[0] > 0.f) ? o[0] : LEAKY * o[0];
        float h1 = (o[1] > 0.f) ? o[1] : LEAKY * o[1];
        float h2 = (o[2] > 0.f) ? o[2] : LEAKY * o[2];
        float h3 = (o[3] > 0.f) ? o[3] : LEAKY * o[3];
        float ss = h0 * h0 + h1 * h1 + h2 * h2 + h3 * h3;
        ss += __shfl_xor(ss, 1, 64);
        ss += __shfl_xor(ss, 2, 64);
        ss += __shfl_xor(ss, 4, 64);       // 8 lanes = one node
        float sc = 1.0f / fmaxf(sqrtf(ss), 1e-12f);
        int node = nb + nI;
        if (node < N) {
            float4 r = {h0 * sc, h1 * sc, h2 * sc, h3 * sc};
            *(float4*)&out[node * 32 + d0] = r;
        }
    }
}

// final = concat(a0, a1, a2); score[b] = dot(final[u], final[NU+i]) over 160 dims
__global__ __launch_bounds__(256) void score_pairs(
    const float* __restrict__ a0, const float* __restrict__ a1,
    const float* __restrict__ a2,
    const int* __restrict__ uid, const int* __restrict__ iid,
    float* __restrict__ out, int B, int NU) {
    int wave = threadIdx.x >> 6, lane = threadIdx.x & 63;
    int p = blockIdx.x * 4 + wave;
    if (p >= B) return;
    int u = uid[p], it = iid[p];
    size_t un = (size_t)u, in = (size_t)(NU + it);
    float s = a0[un * 64 + lane] * a0[in * 64 + lane];
    s = fmaf(a1[un * 64 + lane], a1[in * 64 + lane], s);
    if (lane < 32) s = fmaf(a2[un * 32 + lane], a2[in * 32 + lane], s);
#pragma unroll
    for (int m = 32; m >= 1; m >>= 1) s += __shfl_xor(s, m, 64);
    if (lane == 0) out[p] = s;
}

extern "C" void kernel_launch(void* const* d_in, const int* in_sizes, int n_in,
                              void* d_out, int out_size, void* d_ws, size_t ws_size,
                              hipStream_t stream) {
    const int*   edge_row  = (const int*)d_in[0];
    const int*   edge_col  = (const int*)d_in[1];
    const float* edge_vals = (const float*)d_in[2];
    const float* ue        = (const float*)d_in[3];
    const float* ee        = (const float*)d_in[4];
    const float* W1_0 = (const float*)d_in[5];
    const float* b1_0 = (const float*)d_in[6];
    const float* W2_0 = (const float*)d_in[7];
    const float* b2_0 = (const float*)d_in[8];
    const float* W1_1 = (const float*)d_in[9];
    const float* b1_1 = (const float*)d_in[10];
    const float* W2_1 = (const float*)d_in[11];
    const float* b2_1 = (const float*)d_in[12];
    const int*   uid  = (const int*)d_in[13];
    const int*   iid  = (const int*)d_in[14];
    float* out = (float*)d_out;

    const int E  = in_sizes[0];
    const int NU = in_sizes[3] / 64;
    const int NE = in_sizes[4] / 64;
    const int N  = NU + NE;
    const int B  = in_sizes[13];
    const int G  = (N + SCAN_TILE - 1) / SCAN_TILE;

    char* ws = (char*)d_ws;
    size_t off = 0;
    auto alloc = [&](size_t bytes) -> char* {
        char* p = ws + off;
        off = (off + bytes + 255) & ~(size_t)255;
        return p;
    };
    int*   deg      = (int*)alloc((size_t)N * 4);
    int*   rank     = (int*)alloc((size_t)E * 4);
    int*   row_ptr  = (int*)alloc((size_t)(N + 1) * 4);
    int*   blocksum = (int*)alloc((size_t)1024 * 4);
    int*   blockoff = (int*)alloc((size_t)1024 * 4);
    int2*  csr      = (int2*)alloc((size_t)E * 8);
    float* a0       = (float*)alloc((size_t)N * 64 * 4);
    float* a1       = (float*)alloc((size_t)N * 64 * 4);
    float* a2       = (float*)alloc((size_t)N * 32 * 4);
    (void)ws_size; (void)n_in; (void)out_size; (void)NE;

    zero_i32<<<(N + 255) / 256, 256, 0, stream>>>(deg, N);
    count_edges<<<(E + 255) / 256, 256, 0, stream>>>(edge_row, E, deg, rank);
    scan_phase1<<<G, SCAN_BLOCK, 0, stream>>>(deg, blocksum, N);
    scan_phase2<<<1, 1024, 0, stream>>>(blocksum, blockoff, row_ptr, G, N);
    scan_phase3<<<G, SCAN_BLOCK, 0, stream>>>(deg, blockoff, row_ptr, N);
    fill_csr<<<(E + 255) / 256, 256, 0, stream>>>(edge_row, edge_col, edge_vals,
                                                  rank, row_ptr, E, csr);
    int ntot4 = N * 16, nu4 = NU * 16;
    build_a0<<<(ntot4 + 255) / 256, 256, 0, stream>>>((const float4*)ue, (const float4*)ee,
                                                      (float4*)a0, nu4, ntot4);
    gnn_layer<64><<<(N + 31) / 32, 256, 0, stream>>>(a0, csr, row_ptr,
                                                     W1_0, b1_0, W2_0, b2_0, a1, N);
    gnn_layer<32><<<(N + 31) / 32, 256, 0, stream>>>(a1, csr, row_ptr,
                                                     W1_1, b1_1, W2_1, b2_1, a2, N);
    score_pairs<<<(B + 3) / 4, 256, 0, stream>>>(a0, a1, a2, uid, iid, out, B, NU);
}

// Round 7
// 398.094 us; speedup vs baseline: 1.5150x; 1.1447x over previous
//
#include <hip/hip_runtime.h>
#include <hip/hip_bf16.h>
#include <math.h>

#define LEAKY 0.01f
#define SCAN_BLOCK 256
#define SCAN_ITEMS 4
#define SCAN_TILE (SCAN_BLOCK * SCAN_ITEMS)  // 1024 items per block

struct __align__(8) Bf4 { __hip_bfloat16 a, b, c, d; };

__global__ void zero_i32(int* __restrict__ p, int n) {
    int i = blockIdx.x * blockDim.x + threadIdx.x;
    if (i < n) p[i] = 0;
}

// counts degree AND records each edge's rank within its row (kills fill atomic)
__global__ void count_edges(const int* __restrict__ row, int E,
                            int* __restrict__ deg, int* __restrict__ rank) {
    int i = blockIdx.x * blockDim.x + threadIdx.x;
    if (i < E) rank[i] = atomicAdd(&deg[row[i]], 1);
}

// ---- 3-phase device-wide exclusive scan of deg[N] -> row_ptr[N+1] ----
__global__ __launch_bounds__(SCAN_BLOCK) void scan_phase1(
    const int* __restrict__ deg, int* __restrict__ blocksum, int N) {
    __shared__ int red[SCAN_BLOCK];
    int b = blockIdx.x, t = threadIdx.x;
    int base = b * SCAN_TILE + t * SCAN_ITEMS;
    int s = 0;
#pragma unroll
    for (int j = 0; j < SCAN_ITEMS; j++) {
        int i = base + j;
        if (i < N) s += deg[i];
    }
    red[t] = s;
    __syncthreads();
    for (int off = SCAN_BLOCK / 2; off > 0; off >>= 1) {
        if (t < off) red[t] += red[t + off];
        __syncthreads();
    }
    if (t == 0) blocksum[b] = red[0];
}

__global__ __launch_bounds__(1024) void scan_phase2(
    const int* __restrict__ blocksum, int* __restrict__ blockoff,
    int* __restrict__ row_ptr, int G, int N) {
    __shared__ int sums[1024];
    int t = threadIdx.x;
    sums[t] = (t < G) ? blocksum[t] : 0;
    __syncthreads();
    for (int off = 1; off < 1024; off <<= 1) {
        int v = (t >= off) ? sums[t - off] : 0;
        __syncthreads();
        sums[t] += v;
        __syncthreads();
    }
    if (t < G) blockoff[t] = (t == 0) ? 0 : sums[t - 1];
    if (t == G - 1) row_ptr[N] = sums[t];
}

__global__ __launch_bounds__(SCAN_BLOCK) void scan_phase3(
    const int* __restrict__ deg, const int* __restrict__ blockoff,
    int* __restrict__ row_ptr, int N) {
    __shared__ int red[SCAN_BLOCK];
    int b = blockIdx.x, t = threadIdx.x;
    int base = b * SCAN_TILE + t * SCAN_ITEMS;
    int v[SCAN_ITEMS];
    int s = 0;
#pragma unroll
    for (int j = 0; j < SCAN_ITEMS; j++) {
        int i = base + j;
        v[j] = (i < N) ? deg[i] : 0;
        s += v[j];
    }
    red[t] = s;
    __syncthreads();
    for (int off = 1; off < SCAN_BLOCK; off <<= 1) {
        int x = (t >= off) ? red[t - off] : 0;
        __syncthreads();
        red[t] += x;
        __syncthreads();
    }
    int run = blockoff[b] + ((t == 0) ? 0 : red[t - 1]);
#pragma unroll
    for (int j = 0; j < SCAN_ITEMS; j++) {
        int i = base + j;
        if (i < N) { row_ptr[i] = run; run += v[j]; }
    }
}
// ----------------------------------------------------------------------

// a0 = concat(user_embed, entity_embed) (fp32) + bf16 gather copy
__global__ void build_a0(const float4* __restrict__ ue, const float4* __restrict__ ee,
                         float4* __restrict__ a0, __hip_bfloat16* __restrict__ a0b,
                         int nu4, int ntot4) {
    int i = blockIdx.x * blockDim.x + threadIdx.x;
    if (i < ntot4) {
        float4 v = (i < nu4) ? ue[i] : ee[i - nu4];
        a0[i] = v;
        Bf4 q = {__float2bfloat16(v.x), __float2bfloat16(v.y),
                 __float2bfloat16(v.z), __float2bfloat16(v.w)};
        *(Bf4*)&a0b[(size_t)i * 4] = q;
    }
}

// atomic-free CSR fill using precomputed ranks
__global__ void fill_csr(const int* __restrict__ row, const int* __restrict__ col,
                         const float* __restrict__ val, const int* __restrict__ rank,
                         const int* __restrict__ row_ptr, int E,
                         int2* __restrict__ csr) {
    int i = blockIdx.x * blockDim.x + threadIdx.x;
    if (i < E) {
        int p = row_ptr[row[i]] + rank[i];
        csr[p] = make_int2(col[i], __float_as_int(val[i]));
    }
}

__device__ __forceinline__ void fma4(float o[4], float sv, const float4& wv) {
    o[0] = fmaf(sv, wv.x, o[0]);
    o[1] = fmaf(sv, wv.y, o[1]);
    o[2] = fmaf(sv, wv.z, o[2]);
    o[3] = fmaf(sv, wv.w, o[3]);
}

// Fused GNN layer. Block = 256 thr (4 waves), 8 nodes per wave.
// Phase 1: lane-parallel CSR metadata load (one coalesced fetch for up to 64
//   edges) -> shfl-distribute -> chunks of 8 fully independent bf16 gathers
//   (lanes >= deg shfl col=0/val=0 -> no-op fma on hot row 0). fp32 accumulate.
// Phase 2: register-blocked MLP, weights from global (L1/L2-resident), LDS
//   holds only S rows (stride 132, conflict-free).
template<int DOUT>
__global__ __launch_bounds__(256, 4) void gnn_layer(
    const float* __restrict__ feats, const __hip_bfloat16* __restrict__ featsb,
    const int2* __restrict__ csr, const int* __restrict__ row_ptr,
    const float* __restrict__ W1, const float* __restrict__ b1,
    const float* __restrict__ W2, const float* __restrict__ b2,
    float* __restrict__ out, __hip_bfloat16* __restrict__ outb, int N) {
    __shared__ __align__(16) float S[32 * 132];
    int wv = threadIdx.x >> 6, lane = threadIdx.x & 63;
    int nb = blockIdx.x * 32 + wv * 8;  // first node of this wave

    // ---- phase 1: aggregate 8 nodes ----
    for (int ni = 0; ni < 8; ni++) {
        int node = nb + ni;
        if (node >= N) break;
        float x = feats[(size_t)node * 64 + lane];
        int e0 = row_ptr[node];
        int degn = row_ptr[node + 1] - e0;
        float acc = 0.f;
        int done = 0;
        while (done < degn) {
            int take = min(64, degn - done);
            int2 m = make_int2(0, 0);
            if (lane < take) m = csr[e0 + done + lane];
            int nch = (take + 7) >> 3;
            for (int c2 = 0; c2 < nch; c2++) {
                int base = c2 * 8;
                float fv[8], vv[8];
#pragma unroll
                for (int u = 0; u < 8; u++) {
                    int col = __shfl(m.x, base + u, 64);
                    vv[u] = __int_as_float(__shfl(m.y, base + u, 64));
                    fv[u] = __bfloat162float(featsb[(size_t)col * 64 + lane]);
                }
#pragma unroll
                for (int u = 0; u < 8; u++) acc = fmaf(vv[u], fv[u], acc);
            }
            done += take;
        }
        float* sp = &S[(wv * 8 + ni) * 132];
        sp[lane]      = x + acc;  // s1
        sp[64 + lane] = x * acc;  // s2
    }
    __threadfence_block();  // wave-local LDS write -> cross-lane read ordering

    // ---- phase 2: MLP + epilogue ----
    if constexpr (DOUT == 64) {
        int strip = lane & 15, g = lane >> 4;    // 16 strips x 4 dims; 4 node-pairs
        int d0 = strip * 4;
        float4 b1v = *(const float4*)&b1[d0];
        float4 b2v = *(const float4*)&b2[d0];
        float oa[4] = {b1v.x + b2v.x, b1v.y + b2v.y, b1v.z + b2v.z, b1v.w + b2v.w};
        float ob[4] = {oa[0], oa[1], oa[2], oa[3]};
        const float* spa = &S[(wv * 8 + 2 * g) * 132];
        const float* spb = spa + 132;
#pragma unroll
        for (int half = 0; half < 2; half++) {
            const float* W  = half ? W2 : W1;
            const float* sa = spa + half * 64;
            const float* sb = spb + half * 64;
#pragma unroll 2
            for (int k = 0; k < 64; k += 4) {
                float4 va = *(const float4*)&sa[k];
                float4 vb = *(const float4*)&sb[k];
                float4 wr0 = *(const float4*)&W[(k + 0) * 64 + d0];
                float4 wr1 = *(const float4*)&W[(k + 1) * 64 + d0];
                float4 wr2 = *(const float4*)&W[(k + 2) * 64 + d0];
                float4 wr3 = *(const float4*)&W[(k + 3) * 64 + d0];
                fma4(oa, va.x, wr0); fma4(oa, va.y, wr1);
                fma4(oa, va.z, wr2); fma4(oa, va.w, wr3);
                fma4(ob, vb.x, wr0); fma4(ob, vb.y, wr1);
                fma4(ob, vb.z, wr2); fma4(ob, vb.w, wr3);
            }
        }
#pragma unroll
        for (int t = 0; t < 2; t++) {
            float* o = t ? ob : oa;
            float h0 = (o[0] > 0.f) ? o[0] : LEAKY * o[0];
            float h1 = (o[1] > 0.f) ? o[1] : LEAKY * o[1];
            float h2 = (o[2] > 0.f) ? o[2] : LEAKY * o[2];
            float h3 = (o[3] > 0.f) ? o[3] : LEAKY * o[3];
            float ss = h0 * h0 + h1 * h1 + h2 * h2 + h3 * h3;
            ss += __shfl_xor(ss, 1, 64);
            ss += __shfl_xor(ss, 2, 64);
            ss += __shfl_xor(ss, 4, 64);
            ss += __shfl_xor(ss, 8, 64);   // 16 lanes = one node
            float sc = 1.0f / fmaxf(sqrtf(ss), 1e-12f);
            int node = nb + 2 * g + t;
            if (node < N) {
                float4 r = {h0 * sc, h1 * sc, h2 * sc, h3 * sc};
                *(float4*)&out[(size_t)node * 64 + d0] = r;
                Bf4 q = {__float2bfloat16(r.x), __float2bfloat16(r.y),
                         __float2bfloat16(r.z), __float2bfloat16(r.w)};
                *(Bf4*)&outb[(size_t)node * 64 + d0] = q;
            }
        }
    } else {
        int strip = lane & 7, nI = lane >> 3;    // 8 strips x 4 dims; 8 nodes
        int d0 = strip * 4;
        float4 b1v = *(const float4*)&b1[d0];
        float4 b2v = *(const float4*)&b2[d0];
        float o[4] = {b1v.x + b2v.x, b1v.y + b2v.y, b1v.z + b2v.z, b1v.w + b2v.w};
        const float* sp = &S[(wv * 8 + nI) * 132];
#pragma unroll
        for (int half = 0; half < 2; half++) {
            const float* W  = half ? W2 : W1;
            const float* sv = sp + half * 64;
#pragma unroll 2
            for (int k = 0; k < 64; k += 4) {
                float4 v   = *(const float4*)&sv[k];
                float4 wr0 = *(const float4*)&W[(k + 0) * 32 + d0];
                float4 wr1 = *(const float4*)&W[(k + 1) * 32 + d0];
                float4 wr2 = *(const float4*)&W[(k + 2) * 32 + d0];
                float4 wr3 = *(const float4*)&W[(k + 3) * 32 + d0];
                fma4(o, v.x, wr0); fma4(o, v.y, wr1);
                fma4(o, v.z, wr2); fma4(o, v.w, wr3);
            }
        }
        float h0 = (o[0] > 0.f) ? o[0] : LEAKY * o[0];
        float h1 = (o[1] > 0.f) ? o[1] : LEAKY * o[1];
        float h2 = (o[2] > 0.f) ? o[2] : LEAKY * o[2];
        float h3 = (o[3] > 0.f) ? o[3] : LEAKY * o[3];
        float ss = h0 * h0 + h1 * h1 + h2 * h2 + h3 * h3;
        ss += __shfl_xor(ss, 1, 64);
        ss += __shfl_xor(ss, 2, 64);
        ss += __shfl_xor(ss, 4, 64);       // 8 lanes = one node
        float sc = 1.0f / fmaxf(sqrtf(ss), 1e-12f);
        int node = nb + nI;
        if (node < N) {
            float4 r = {h0 * sc, h1 * sc, h2 * sc, h3 * sc};
            *(float4*)&out[(size_t)node * 32 + d0] = r;
        }
    }
}

// final = concat(a0, a1, a2); score[b] = dot(final[u], final[NU+i]) over 160 dims
__global__ __launch_bounds__(256) void score_pairs(
    const float* __restrict__ a0, const float* __restrict__ a1,
    const float* __restrict__ a2,
    const int* __restrict__ uid, const int* __restrict__ iid,
    float* __restrict__ out, int B, int NU) {
    int wave = threadIdx.x >> 6, lane = threadIdx.x & 63;
    int p = blockIdx.x * 4 + wave;
    if (p >= B) return;
    int u = uid[p], it = iid[p];
    size_t un = (size_t)u, in = (size_t)(NU + it);
    float s = a0[un * 64 + lane] * a0[in * 64 + lane];
    s = fmaf(a1[un * 64 + lane], a1[in * 64 + lane], s);
    if (lane < 32) s = fmaf(a2[un * 32 + lane], a2[in * 32 + lane], s);
#pragma unroll
    for (int m = 32; m >= 1; m >>= 1) s += __shfl_xor(s, m, 64);
    if (lane == 0) out[p] = s;
}

extern "C" void kernel_launch(void* const* d_in, const int* in_sizes, int n_in,
                              void* d_out, int out_size, void* d_ws, size_t ws_size,
                              hipStream_t stream) {
    const int*   edge_row  = (const int*)d_in[0];
    const int*   edge_col  = (const int*)d_in[1];
    const float* edge_vals = (const float*)d_in[2];
    const float* ue        = (const float*)d_in[3];
    const float* ee        = (const float*)d_in[4];
    const float* W1_0 = (const float*)d_in[5];
    const float* b1_0 = (const float*)d_in[6];
    const float* W2_0 = (const float*)d_in[7];
    const float* b2_0 = (const float*)d_in[8];
    const float* W1_1 = (const float*)d_in[9];
    const float* b1_1 = (const float*)d_in[10];
    const float* W2_1 = (const float*)d_in[11];
    const float* b2_1 = (const float*)d_in[12];
    const int*   uid  = (const int*)d_in[13];
    const int*   iid  = (const int*)d_in[14];
    float* out = (float*)d_out;

    const int E  = in_sizes[0];
    const int NU = in_sizes[3] / 64;
    const int NE = in_sizes[4] / 64;
    const int N  = NU + NE;
    const int B  = in_sizes[13];
    const int G  = (N + SCAN_TILE - 1) / SCAN_TILE;

    char* ws = (char*)d_ws;
    size_t off = 0;
    auto alloc = [&](size_t bytes) -> char* {
        char* p = ws + off;
        off = (off + bytes + 255) & ~(size_t)255;
        return p;
    };
    int*   deg      = (int*)alloc((size_t)N * 4);
    int*   rank     = (int*)alloc((size_t)E * 4);
    int*   row_ptr  = (int*)alloc((size_t)(N + 1) * 4);
    int*   blocksum = (int*)alloc((size_t)1024 * 4);
    int*   blockoff = (int*)alloc((size_t)1024 * 4);
    int2*  csr      = (int2*)alloc((size_t)E * 8);
    float* a0       = (float*)alloc((size_t)N * 64 * 4);
    float* a1       = (float*)alloc((size_t)N * 64 * 4);
    float* a2       = (float*)alloc((size_t)N * 32 * 4);
    __hip_bfloat16* a0b = (__hip_bfloat16*)alloc((size_t)N * 64 * 2);
    __hip_bfloat16* a1b = (__hip_bfloat16*)alloc((size_t)N * 64 * 2);
    (void)ws_size; (void)n_in; (void)out_size; (void)NE;

    zero_i32<<<(N + 255) / 256, 256, 0, stream>>>(deg, N);
    count_edges<<<(E + 255) / 256, 256, 0, stream>>>(edge_row, E, deg, rank);
    scan_phase1<<<G, SCAN_BLOCK, 0, stream>>>(deg, blocksum, N);
    scan_phase2<<<1, 1024, 0, stream>>>(blocksum, blockoff, row_ptr, G, N);
    scan_phase3<<<G, SCAN_BLOCK, 0, stream>>>(deg, blockoff, row_ptr, N);
    fill_csr<<<(E + 255) / 256, 256, 0, stream>>>(edge_row, edge_col, edge_vals,
                                                  rank, row_ptr, E, csr);
    int ntot4 = N * 16, nu4 = NU * 16;
    build_a0<<<(ntot4 + 255) / 256, 256, 0, stream>>>((const float4*)ue, (const float4*)ee,
                                                      (float4*)a0, a0b, nu4, ntot4);
    gnn_layer<64><<<(N + 31) / 32, 256, 0, stream>>>(a0, a0b, csr, row_ptr,
                                                     W1_0, b1_0, W2_0, b2_0, a1, a1b, N);
    gnn_layer<32><<<(N + 31) / 32, 256, 0, stream>>>(a1, a1b, csr, row_ptr,
                                                     W1_1, b1_1, W2_1, b2_1, a2, nullptr, N);
    score_pairs<<<(B + 3) / 4, 256, 0, stream>>>(a0, a1, a2, uid, iid, out, B, NU);
}